// Round 2
// baseline (74.733 us; speedup 1.0000x reference)
//
#include <hip/hip_runtime.h>

// SGNN projection, round 13 (resubmit after infra failure): 2 batch rows per block.
//
// Math (M = 2^31-1 Mersenne, HALF = 2^30-1):
//   centered(v) = ((v + HALF) mod M) - HALF  ->  p2 = v*seed + HALF.
//   Fold: s = (p2>>31) + (p2 & M) <= 2^32-4 < 2M ALWAYS (v,seed <= 2^31-2).
//   Residue: r = min_u32(s, s - M) -- exact branchless mod.
//   Zero slots give r = HALF exactly, so summing N8 slots (compacted row
//   zero-filled to 128) and subtracting N8*HALF equals the exact centered sum
//   over the cnt real elements, for ANY N8 in [cnt, 128].
//   Pair-sum: r <= 2^31-2, so r_a + r_b fits u32 exactly -> halves the 64-bit
//   accumulate traffic.
//
// Round-13 structure: one block per PAIR of batch rows (704 thr = 11 waves).
//   Grid 512 = exactly 2 blocks/CU co-resident -> ONE dispatch round (was 2);
//   stage of one block hides under compute of its CU-mate with no round
//   boundary. Waves 0-5 ballot-compact the 6 (row,partition) LDS rows using
//   int2 (8B) loads; compaction order within a row is irrelevant (sum is
//   commutative). One barrier; then each thread h=tid computes BOTH rows
//   sequentially (seed load, h/partition decode, trip-count logic amortized
//   2x; sequential rows keep VGPR pressure ~= the 1-row kernel so 22 waves/CU
//   residency is preserved).

#define M31    2147483647u   // 2^31 - 1
#define HALF_B 1073741823u   // 2^30 - 1

__device__ __forceinline__ unsigned relem(unsigned v, unsigned long long seed) {
    const unsigned long long p2 = (unsigned long long)v * seed + (unsigned long long)HALF_B;
    const unsigned lo = (unsigned)p2;
    const unsigned hi = (unsigned)(p2 >> 32);
    const unsigned s  = __builtin_amdgcn_alignbit(hi, lo, 31) + (lo & 0x7FFFFFFFu);
    return min(s, s - M31);              // exact (v*seed+HALF) mod M
}

__global__ __launch_bounds__(704) void sgnn_fused2_kernel(
    const int* __restrict__ sig,    // [3, B, 128]
    const int* __restrict__ mask,   // [3, B, 128]
    const int* __restrict__ seeds,  // [672]
    float* __restrict__ out,        // [B, 672]
    int nbatch)
{
    __shared__ unsigned srow[2][3][128];  // [row in pair][partition][compacted]
    __shared__ float    sinv[2][3];       // 1/(max(cnt,1)*HALF)
    __shared__ unsigned scnt[2][3];       // raw valid count

    const unsigned tid  = threadIdx.x;
    const unsigned lane = tid & 63u;
    const unsigned W    = tid >> 6;       // wave id in [0,11)
    const unsigned b0   = blockIdx.x << 1;

    // ---- Stage: waves 0-5 compact (row rr, partition pp) into LDS ----
    if (W < 6u) {
        const unsigned rr   = W & 1u;     // which row of the pair
        const unsigned pp   = W >> 1;     // partition 0..2
        const unsigned brow = b0 + rr;
        if (brow < (unsigned)nbatch) {    // wave-uniform guard (safe ballots)
            const unsigned base = (pp * (unsigned)nbatch + brow) * 128u + lane * 2u;
            const int2 sg = *(const int2*)&sig[base];   // 8B coalesced
            const int2 mk = *(const int2*)&mask[base];

            const unsigned long long bx = __ballot(mk.x != 0);
            const unsigned long long by = __ballot(mk.y != 0);
            const unsigned long long lt = (1ULL << lane) - 1ULL;
            const unsigned cx   = (unsigned)__popcll(bx);
            const unsigned cnt  = cx + (unsigned)__popcll(by);
            // interleaved element order; compaction order is irrelevant to the sum
            if (mk.x) srow[rr][pp][(unsigned)__popcll(bx & lt)]      = (unsigned)sg.x;
            if (mk.y) srow[rr][pp][cx + (unsigned)__popcll(by & lt)] = (unsigned)sg.y;
            // zero-fill [cnt,128) -- disjoint from compacted [0,cnt), no race
            if (cnt + lane < 128u)        srow[rr][pp][cnt + lane]        = 0u;
            if (cnt + 64u + lane < 128u)  srow[rr][pp][cnt + 64u + lane]  = 0u;

            if (lane == 0) {
                const unsigned c = cnt ? cnt : 1u;
                sinv[rr][pp] = 1.0f / ((float)c * 1073741823.0f);
                scnt[rr][pp] = cnt;
            }
        }
    }
    __syncthreads();

    // ---- Compute: flat h = tid, 672 outputs over 11 waves, 2 rows each ----
    const unsigned h     = tid;
    const bool     valid = (h < 672u);
    const unsigned h_c   = valid ? h : 671u;
    const unsigned p     = (h_c < 112u) ? 0u : (h_c < 336u) ? 1u : 2u;

    // wave-uniform trip count base: partitions this wave spans (<=2)
    const unsigned wh0 = tid & ~63u;
    const unsigned wh1 = (wh0 + 63u < 671u) ? wh0 + 63u : 671u;
    const unsigned plo = (wh0 < 112u) ? 0u : (wh0 < 336u) ? 1u : 2u;
    const unsigned phi = (wh1 < 112u) ? 0u : (wh1 < 336u) ? 1u : 2u;

    const unsigned long long seed = (unsigned long long)(unsigned)seeds[h_c];

#pragma unroll
    for (unsigned r = 0; r < 2u; ++r) {
        const unsigned brow = b0 + r;
        if (brow < (unsigned)nbatch) {
            unsigned nmax = max(scnt[r][plo], scnt[r][phi]);
            nmax = (nmax + 7u) & ~7u;                    // step-8 loop, pads exact
            nmax = __builtin_amdgcn_readfirstlane(nmax); // -> SGPR loop bound

            const unsigned* __restrict__ rp = srow[r][p]; // <=2 distinct rows/wave

            unsigned long long sum0 = 0, sum1 = 0;       // exact: <=64 adds of <2^32
            for (unsigned mm = 0; mm < nmax; mm += 8u) {
                const uint4 a = *(const uint4*)&rp[mm];      // ds_read_b128
                const uint4 c = *(const uint4*)&rp[mm + 4u];
                sum0 += (unsigned long long)(relem(a.x, seed) + relem(a.y, seed));
                sum1 += (unsigned long long)(relem(a.z, seed) + relem(a.w, seed));
                sum0 += (unsigned long long)(relem(c.x, seed) + relem(c.y, seed));
                sum1 += (unsigned long long)(relem(c.z, seed) + relem(c.w, seed));
            }

            if (valid) {
                const long long centered = (long long)(sum0 + sum1)
                                         - (long long)nmax * 1073741823LL;
                out[brow * 672u + h] = (float)centered * sinv[r][p];
            }
        }
    }
}

extern "C" void kernel_launch(void* const* d_in, const int* in_sizes, int n_in,
                              void* d_out, int out_size, void* d_ws, size_t ws_size,
                              hipStream_t stream) {
    const int* sig   = (const int*)d_in[0];
    const int* mask  = (const int*)d_in[1];
    const int* seeds = (const int*)d_in[2];
    float* out = (float*)d_out;

    const int nbatch = in_sizes[0] / (3 * 128);  // 1024
    const int nblk   = (nbatch + 1) / 2;         // 512: 2 rows per block
    sgnn_fused2_kernel<<<dim3(nblk), dim3(704), 0, stream>>>(sig, mask, seeds, out, nbatch);
}

// Round 3
// 74.328 us; speedup vs baseline: 1.0054x; 1.0054x over previous
//
#include <hip/hip_runtime.h>

// SGNN projection, round 14: high-occupancy 256-thread blocks.
//
// Math (M = 2^31-1 Mersenne, HALF = 2^30-1):
//   centered(v) = ((v + HALF) mod M) - HALF  ->  p2 = v*seed + HALF.
//   Fold: s = (p2>>31) + (p2 & M) <= 2^32-4 < 2M ALWAYS (v,seed <= 2^31-2).
//   Residue: r = min_u32(s, s - M) -- exact branchless mod.
//   Zero slots give r = HALF exactly, so summing N8 slots (compacted row
//   zero-filled to 128) and subtracting N8*HALF equals the exact centered sum
//   over the cnt real elements, for ANY N8 in [cnt, 128].
//   Pair-sum: r <= 2^31-2, so r_a + r_b fits u32 exactly.
//
// Round-14 structure: grid (3, nbatch); block (c, b) = 256 thr (4 waves)
// computes outputs h in [224c, 224c+224) of row b. Chunk boundaries align
// with partitions so each block touches <=2 of them:
//   c=0 -> {0,1}, c=1 -> {1,2}, c=2 -> {2};  lds slot lp = p - c.
// Waves 0..1 ballot-compact partition (c+W) into LDS slot W (int2 loads);
// one barrier; every thread computes ONE output over its row slice.
// Why: r12/r13 were pinned at 22 waves/CU (11-wave blocks, 32-wave cap ->
// 2 blocks/CU, 10 slots wasted). 256-thr blocks + __launch_bounds__(256,8)
// -> 8 blocks/CU = 32 waves/CU (+45% latency hiding), no dead 673..703
// threads, shorter serial loop per thread. Tests H1 (kernel latency-bound)
// vs H2 (kernel already at VALU roofline, residual = harness fill/reset).

#define M31    2147483647u   // 2^31 - 1
#define HALF_B 1073741823u   // 2^30 - 1

__device__ __forceinline__ unsigned relem(unsigned v, unsigned long long seed) {
    const unsigned long long p2 = (unsigned long long)v * seed + (unsigned long long)HALF_B;
    const unsigned lo = (unsigned)p2;
    const unsigned hi = (unsigned)(p2 >> 32);
    const unsigned s  = __builtin_amdgcn_alignbit(hi, lo, 31) + (lo & 0x7FFFFFFFu);
    return min(s, s - M31);              // exact (v*seed+HALF) mod M
}

__global__ __launch_bounds__(256, 8) void sgnn_hocc_kernel(
    const int* __restrict__ sig,    // [3, B, 128]
    const int* __restrict__ mask,   // [3, B, 128]
    const int* __restrict__ seeds,  // [672]
    float* __restrict__ out,        // [B, 672]
    int nbatch)
{
    __shared__ unsigned srow[2][128];  // [lds slot][compacted, zero-filled]
    __shared__ float    sinv[2];       // 1/(max(cnt,1)*HALF)
    __shared__ unsigned scnt[2];       // raw valid count

    const unsigned tid  = threadIdx.x;
    const unsigned lane = tid & 63u;
    const unsigned W    = tid >> 6;        // wave id 0..3
    const unsigned c    = blockIdx.x;      // chunk 0..2
    const unsigned b    = blockIdx.y;      // batch row

    // ---- Stage: wave W in {0,1} compacts partition (c+W) into slot W ----
    if (W < 2u && c + W < 3u) {            // wave-uniform guard: ballots safe
        const unsigned p    = c + W;
        const unsigned base = (p * (unsigned)nbatch + b) * 128u + lane * 2u;
        const int2 sg = *(const int2*)&sig[base];   // 8B coalesced
        const int2 mk = *(const int2*)&mask[base];

        const unsigned long long bx = __ballot(mk.x != 0);
        const unsigned long long by = __ballot(mk.y != 0);
        const unsigned long long lt = (1ULL << lane) - 1ULL;
        const unsigned cx   = (unsigned)__popcll(bx);
        const unsigned cnt  = cx + (unsigned)__popcll(by);
        // compaction order is irrelevant (sum is commutative)
        if (mk.x) srow[W][(unsigned)__popcll(bx & lt)]      = (unsigned)sg.x;
        if (mk.y) srow[W][cx + (unsigned)__popcll(by & lt)] = (unsigned)sg.y;
        // zero-fill [cnt,128) -- disjoint from compacted [0,cnt), no race
        if (cnt + lane < 128u)        srow[W][cnt + lane]        = 0u;
        if (cnt + 64u + lane < 128u)  srow[W][cnt + 64u + lane]  = 0u;

        if (lane == 0) {
            const unsigned cc = cnt ? cnt : 1u;
            sinv[W] = 1.0f / ((float)cc * 1073741823.0f);
            scnt[W] = cnt;
        }
    }
    __syncthreads();

    // ---- Compute: 224 outputs over 4 waves (threads 224..255 redundant) ----
    const bool     valid = (tid < 224u);
    const unsigned ht    = valid ? tid : 223u;          // chunk-local output
    const unsigned h     = 224u * c + ht;               // global output index
    const unsigned p     = (h < 112u) ? 0u : (h < 336u) ? 1u : 2u;
    const unsigned lp    = p - c;                       // LDS slot

    // wave-uniform trip count: partitions this wave spans (<=2)
    const unsigned e0  = tid & ~63u;                    // 0,64,128,192
    const unsigned e1  = (e0 + 63u < 223u) ? e0 + 63u : 223u;
    const unsigned g0  = 224u * c + e0;
    const unsigned g1  = 224u * c + e1;
    const unsigned plo = (g0 < 112u) ? 0u : (g0 < 336u) ? 1u : 2u;
    const unsigned phi = (g1 < 112u) ? 0u : (g1 < 336u) ? 1u : 2u;
    unsigned nmax = max(scnt[plo - c], scnt[phi - c]);
    nmax = (nmax + 7u) & ~7u;                           // step-8 loop, pads exact
    nmax = __builtin_amdgcn_readfirstlane(nmax);        // -> SGPR loop bound

    const unsigned long long seed = (unsigned long long)(unsigned)seeds[h];
    const unsigned* __restrict__ rp = srow[lp];         // <=2 distinct rows/wave

    unsigned long long sum0 = 0, sum1 = 0;              // exact: <=64 adds of <2^32
    for (unsigned mm = 0; mm < nmax; mm += 8u) {
        const uint4 a = *(const uint4*)&rp[mm];         // ds_read_b128
        const uint4 q = *(const uint4*)&rp[mm + 4u];
        sum0 += (unsigned long long)(relem(a.x, seed) + relem(a.y, seed));
        sum1 += (unsigned long long)(relem(a.z, seed) + relem(a.w, seed));
        sum0 += (unsigned long long)(relem(q.x, seed) + relem(q.y, seed));
        sum1 += (unsigned long long)(relem(q.z, seed) + relem(q.w, seed));
    }

    if (valid) {
        const long long centered = (long long)(sum0 + sum1)
                                 - (long long)nmax * 1073741823LL;
        out[b * 672u + h] = (float)centered * sinv[lp];
    }
}

extern "C" void kernel_launch(void* const* d_in, const int* in_sizes, int n_in,
                              void* d_out, int out_size, void* d_ws, size_t ws_size,
                              hipStream_t stream) {
    const int* sig   = (const int*)d_in[0];
    const int* mask  = (const int*)d_in[1];
    const int* seeds = (const int*)d_in[2];
    float* out = (float*)d_out;

    const int nbatch = in_sizes[0] / (3 * 128);  // 1024
    sgnn_hocc_kernel<<<dim3(3, nbatch), dim3(256), 0, stream>>>(sig, mask, seeds, out, nbatch);
}